// Round 13
// baseline (316.722 us; speedup 1.0000x reference)
//
#include <hip/hip_runtime.h>

typedef unsigned short u16;
typedef __bf16 bf16x8_t __attribute__((ext_vector_type(8)));
typedef unsigned short u16x8_t __attribute__((ext_vector_type(8)));
typedef float f32x4_t __attribute__((ext_vector_type(4)));

__device__ __forceinline__ u16 f2bf(float f) {
  unsigned u = __builtin_bit_cast(unsigned, f);
  u += 0x7FFFu + ((u >> 16) & 1u);  // round-to-nearest-even
  return (u16)(u >> 16);
}
__device__ __forceinline__ float bf2f(u16 h) {
  unsigned u = ((unsigned)h) << 16;
  return __builtin_bit_cast(float, u);
}

typedef __attribute__((address_space(1))) const unsigned gas_u32;
typedef __attribute__((address_space(3))) unsigned las_u32;
__device__ __forceinline__ void gload16(const void* g, void* l) {
  __builtin_amdgcn_global_load_lds((gas_u32*)g, (las_u32*)l, 16, 0, 0);
}

#define SBAR()                                  \
  do {                                          \
    __builtin_amdgcn_sched_barrier(0);          \
    asm volatile("" ::: "memory");              \
    __builtin_amdgcn_s_barrier();               \
    asm volatile("" ::: "memory");              \
    __builtin_amdgcn_sched_barrier(0);          \
  } while (0)
#define VM0() asm volatile("s_waitcnt vmcnt(0)" ::: "memory")
#define VM10() asm volatile("s_waitcnt vmcnt(10)" ::: "memory")
#define VM12() asm volatile("s_waitcnt vmcnt(12)" ::: "memory")
#define LGKM0() asm volatile("s_waitcnt lgkmcnt(0)" ::: "memory")

// ---------------- cast weights fp32->bf16: layout [w1; w3; w2; w4] -----------
__global__ __launch_bounds__(256) void cast4_kernel(
    const float* __restrict__ a0, const float* __restrict__ a1,
    const float* __restrict__ a2, const float* __restrict__ a3,
    u16* __restrict__ out) {
  const int z = blockIdx.z;
  const float* a = (z == 0) ? a0 : (z == 1) ? a1 : (z == 2) ? a2 : a3;
  const int i = blockIdx.x * 256 + threadIdx.x;
  out[(size_t)z * 524288 + i] = f2bf(a[i]);
}

// ---------------- concat b1,b3 -> [1024] -------------------------------------
__global__ __launch_bounds__(256) void bcat_kernel(
    const float* __restrict__ b1, const float* __restrict__ b3,
    float* __restrict__ o) {
  const int i = blockIdx.x * 256 + threadIdx.x;
  o[i] = (i < 512) ? b1[i] : b3[i - 512];
}

// ---------------- fp32 [R,C] -> bf16 [C,R] (batched) --------------------------
__global__ __launch_bounds__(256) void cast_transpose_kernel(
    const float* __restrict__ in, u16* __restrict__ out, int R, int C,
    long sIn, long sOut) {
  __shared__ u16 t[32][33];
  const int b = blockIdx.z;
  in += (long)b * sIn;
  out += (long)b * sOut;
  const int c0 = blockIdx.x * 32, r0 = blockIdx.y * 32;
  const int tx = threadIdx.x, ty = threadIdx.y;
#pragma unroll
  for (int i = 0; i < 32; i += 8)
    t[ty + i][tx] = f2bf(in[(long)(r0 + ty + i) * C + c0 + tx]);
  __syncthreads();
#pragma unroll
  for (int i = 0; i < 32; i += 8)
    out[(long)(c0 + ty + i) * R + r0 + tx] = t[tx][ty + i];
}

// ---------------- bf16 [R,C] -> [C,R], 64x64 tiles, u32-packed ---------------
__global__ __launch_bounds__(256) void transpose64(
    const u16* __restrict__ in, u16* __restrict__ out, int R, int C, long sIn,
    long sOut) {
  __shared__ u16 t[64][66];
  const int b = blockIdx.z;
  in += (long)b * sIn;
  out += (long)b * sOut;
  const int c0 = blockIdx.x * 64, r0 = blockIdx.y * 64;
  const int tx = threadIdx.x & 31, ty = threadIdx.x >> 5;
#pragma unroll
  for (int i = 0; i < 64; i += 8) {
    unsigned v = *(const unsigned*)&in[(long)(r0 + ty + i) * C + c0 + 2 * tx];
    t[ty + i][2 * tx] = (u16)v;
    t[ty + i][2 * tx + 1] = (u16)(v >> 16);
  }
  __syncthreads();
#pragma unroll
  for (int i = 0; i < 64; i += 8) {
    unsigned lo = t[2 * tx][ty + i], hi = t[2 * tx + 1][ty + i];
    *(unsigned*)&out[(long)(c0 + ty + i) * R + r0 + 2 * tx] = lo | (hi << 16);
  }
}

// ---------------- shared staging/fragment macros (8-phase 256^2 template) ----
#define STG_A(bufv, h, kt)                                          \
  do {                                                              \
    const char* g_ = Ag + (size_t)(kt) * 128 + (size_t)(h)*AH;      \
    char* d_ = sAd + (bufv)*32768 + (h)*16384;                      \
    gload16(g_, d_);                                                \
    gload16(g_ + AC, d_ + 8192);                                    \
  } while (0)
#define STG_B(bufv, h, kt)                                          \
  do {                                                              \
    const char* g_ = Bg + (size_t)(kt) * 128 + (size_t)(h)*BH;      \
    char* d_ = sBd + (bufv)*32768 + (h)*16384;                      \
    gload16(g_, d_);                                                \
    gload16(g_ + BC, d_ + 8192);                                    \
  } while (0)
#define LOAD_A(bufv, mh)                                                     \
  _Pragma("unroll") for (int m = 0; m < 4; m++) {                            \
    const int lr_ = (mh)*128 + wr * 64 + m * 16 + l15;                       \
    af[m][0] = *(const bf16x8_t*)(lds + (bufv)*32768 + lr_ * 128 + koff0);   \
    af[m][1] =                                                               \
        *(const bf16x8_t*)(lds + (bufv)*32768 + lr_ * 128 + (koff0 ^ 64));   \
  }
#define LOAD_B(bufv, nh)                                                     \
  _Pragma("unroll") for (int n = 0; n < 2; n++) {                            \
    const int lr_ = (nh)*128 + wc * 32 + n * 16 + l15;                       \
    bfr[(nh)*2 + n][0] =                                                     \
        *(const bf16x8_t*)(lds + 65536 + (bufv)*32768 + lr_ * 128 + koff0);  \
    bfr[(nh)*2 + n][1] = *(const bf16x8_t*)(lds + 65536 + (bufv)*32768 +     \
                                            lr_ * 128 + (koff0 ^ 64));       \
  }
#define MMA(mh, nh)                                                          \
  __builtin_amdgcn_s_setprio(1);                                            \
  _Pragma("unroll") for (int m = 0; m < 4; m++)                              \
      _Pragma("unroll") for (int n = 0; n < 2; n++)                          \
          _Pragma("unroll") for (int kk = 0; kk < 2; kk++)                   \
              acc[(mh)*4 + m][(nh)*2 + n] =                                  \
      __builtin_amdgcn_mfma_f32_16x16x32_bf16(                               \
          af[m][kk], bfr[(nh)*2 + n][kk], acc[(mh)*4 + m][(nh)*2 + n], 0, 0, \
          0);                                                                \
  __builtin_amdgcn_s_setprio(0);

// ---------------- gemm8<MODE>: 256x256, 8 waves, 8-phase, XOR-swizzled LDS ---
// Mainloop = verified round-12 deep ledger (FIFO A0,B0,B1,A1; VM12/VM10/VM12).
// NEW (round 13): LDS-staged vectorized epilogues. After VM0+barrier the
// mainloop LDS is dead; acc (+bias/exp/invS transform) is staged to LDS
// row-major [rows][256+16pad] u16 (or [64][256+8pad] f32 for MODE 2), then
// re-read thread-row-contiguous and stored as 16B dwordx4 (128 scalar stores
// -> 8-16 coalesced). MODE 1 row-sums move to the re-read side (32-lane shfl,
// 9 partials/row). MODE 2 adds float4 resid reads.
template <int MODE>
__global__ __launch_bounds__(512, 2) void gemm8(
    const u16* __restrict__ A, const u16* __restrict__ B,
    void* __restrict__ C0, void* __restrict__ C1, void* __restrict__ C2,
    const u16* __restrict__ W2, const float* __restrict__ bias,
    const float* __restrict__ bias2, const float* __restrict__ resid,
    float* __restrict__ stats) {
  constexpr int LDA_ = (MODE == 0) ? 1024 : (MODE == 3) ? 2304 : 512;
  constexpr int LDB_ = (MODE == 0) ? 1024 : (MODE == 3) ? 2304 : 512;
  constexpr int KK = (MODE == 0) ? 1024 : (MODE == 3) ? 2304 : 512;
  constexpr int NT = KK >> 6;
  constexpr size_t AH = 64ull * LDA_ * 2, AC = 128ull * LDA_ * 2;
  constexpr size_t BH = 32ull * LDB_ * 2, BC = 128ull * LDB_ * 2;

  __shared__ alignas(16) char lds[131072];
  const int tid = threadIdx.x;
  const int w = tid >> 6, l = tid & 63;
  const int wr = w >> 2, wc = w & 3;
  const int l15 = l & 15, lhi = l >> 4;
  const int koff0 = (lhi * 16) ^ ((l & 7) << 4);

  unsigned bx, by, bz;
  bool roleB = false;
  if constexpr (MODE == 0) {
    unsigned bid = blockIdx.x;                      // 1D grid, 432 blocks
    unsigned swz = (bid & 7u) * 54u + (bid >> 3);   // XCD chunk = 54
    roleB = (swz >= 288u);
    unsigned s = roleB ? swz - 288u : swz;
    if (roleB) { bx = s % 2u; by = (s / 2u) % 9u; bz = s / 18u; }
    else       { bx = s % 9u; by = (s / 9u) % 4u; bz = s / 36u; }
  } else {
    const unsigned gx = gridDim.x, gy = gridDim.y;
    const unsigned nb = gx * gy * gridDim.z;
    unsigned bid = blockIdx.x + gx * (blockIdx.y + gy * blockIdx.z);
    bid = (bid & 7u) * (nb >> 3) + (bid >> 3);
    bx = bid % gx;
    unsigned t1 = bid / gx;
    by = t1 % gy;
    bz = t1 / gy;
  }
  const int rowbase = by * 256, colbase = bx * 256;

  const u16* Abase;
  const u16* Bbase;
  if constexpr (MODE == 0) {
    Abase = roleB ? (B + (size_t)bz * 2359296) : A;
    Bbase = roleB ? W2 : (B + (size_t)bz * 2359296);
  } else if constexpr (MODE == 1) {
    Abase = A + (size_t)bz * 1179648;
    Bbase = B + (size_t)bz * 1179648;
  } else if constexpr (MODE == 3) {
    Abase = A + (size_t)bz * 5308416;
    Bbase = B + (size_t)bz * 1179648;
  } else {
    Abase = A;
    Bbase = B + (size_t)bz * 1179648;
  }

  const int sub = tid >> 3;
  const int kb = ((tid & 7) * 16) ^ ((sub & 7) << 4);
  const char* Ag = (const char*)(Abase + (size_t)(rowbase + sub) * LDA_) + kb;
  const char* Bg =
      (const char*)(Bbase + (size_t)(colbase + (sub >> 5) * 64 + (sub & 31)) *
                                LDB_) +
      kb;
  char* sAd = lds + w * 1024;
  char* sBd = lds + 65536 + w * 1024;

  f32x4_t acc[8][4] = {};
  bf16x8_t af[4][2], bfr[4][2];

  // prologue: tile0 + tile1 fully staged, per-tile FIFO order A0,B0,B1,A1
  STG_A(0, 0, 0); STG_B(0, 0, 0);
  STG_B(0, 1, 0); STG_A(0, 1, 0);
  STG_A(1, 0, 1); STG_B(1, 0, 1);
  STG_B(1, 1, 1); STG_A(1, 1, 1);
  VM12();
  SBAR();

  for (int t = 0; t < NT; ++t) {
    const int c = t & 1;
    const int tn2 = (t + 2 < NT) ? t + 2 : NT - 1;
    LOAD_A(c, 0);
    LOAD_B(c, 0);
    SBAR();
    MMA(0, 0);
    VM10();
    SBAR();
    LOAD_B(c, 1);
    STG_A(c, 0, tn2);
    STG_B(c, 0, tn2);
    SBAR();
    MMA(0, 1);
    VM12();
    SBAR();
    LOAD_A(c, 1);
    STG_B(c, 1, tn2);
    SBAR();
    MMA(1, 0);
    SBAR();
    STG_A(c, 1, tn2);
    VM12();
    SBAR();
    MMA(1, 1);
    SBAR();
  }

  // ------------- LDS-staged epilogue -------------
  VM0();   // all in-flight gload_lds landed before we overwrite LDS
  SBAR();

  if constexpr (MODE == 2) {
    // fp32 out = acc + bias + resid; 4 chunks of 64 rows, [64][264] f32.
    constexpr int PF = 264;
    float* ebf = (float*)lds;
    float* Cp = (float*)C0 + (size_t)bz * 2359296;
    const float* rp = resid + (size_t)bz * 2359296;
#pragma unroll
    for (int h = 0; h < 4; ++h) {
#pragma unroll
      for (int m2 = 0; m2 < 2; m2++) {
        const int mf = h * 2 + m2;
#pragma unroll
        for (int r = 0; r < 4; r++) {
          const int lr = wr * 32 + m2 * 16 + lhi * 4 + r;
          const float bv = bias[rowbase + wr * 128 + mf * 16 + lhi * 4 + r];
#pragma unroll
          for (int nf = 0; nf < 4; nf++)
            ebf[lr * PF + wc * 64 + nf * 16 + l15] = acc[mf][nf][r] + bv;
        }
      }
      LGKM0();
      SBAR();
#pragma unroll
      for (int i = 0; i < 8; i++) {
        const int flat = i * 512 + tid;
        const int rr = flat >> 6, cg = flat & 63;
        f32x4_t v = *(const f32x4_t*)&ebf[rr * PF + cg * 4];
        const int ro = (rr >> 5) * 128 + h * 32 + (rr & 31);
        const size_t gidx = (size_t)(rowbase + ro) * 2304 + colbase + cg * 4;
        const f32x4_t rv = *(const f32x4_t*)&rp[gidx];
        v[0] += rv[0]; v[1] += rv[1]; v[2] += rv[2]; v[3] += rv[3];
        *(f32x4_t*)&Cp[gidx] = v;
      }
      SBAR();
    }
  } else {
    // bf16 out, 2 chunks of 128 rows, [128][272] u16.
    constexpr int P = 272;
    u16* eb = (u16*)lds;
    u16* Cp;
    int ldc, rowout0;
    if constexpr (MODE == 0) {
      if (!roleB) {
        const int which = rowbase >> 9;  // uniform per block
        Cp = (u16*)(which ? C1 : C0) + (size_t)bz * 1179648;
        ldc = 2304;
        rowout0 = rowbase - which * 512;
      } else {
        Cp = (u16*)C2 + (size_t)bz * 1179648;
        ldc = 512;
        rowout0 = rowbase;
      }
    } else if constexpr (MODE == 1) {
      Cp = (u16*)C0 + (size_t)bz * 5308416;
      ldc = 2304;
      rowout0 = rowbase;
    } else {  // MODE 3
      Cp = (u16*)C0 + (size_t)bz * 1179648;
      ldc = 512;
      rowout0 = rowbase;
    }
#pragma unroll
    for (int h = 0; h < 2; ++h) {
#pragma unroll
      for (int m2 = 0; m2 < 4; m2++) {
        const int mf = h * 4 + m2;
#pragma unroll
        for (int r = 0; r < 4; r++) {
          const int lr = wr * 64 + m2 * 16 + lhi * 4 + r;
          const int ro = wr * 128 + mf * 16 + lhi * 4 + r;
          float addv = 0.f, mulv = 1.f;
          if constexpr (MODE == 0) {
            if (!roleB) addv = bias[rowbase + ro];
          } else if constexpr (MODE == 3) {
            mulv = stats[(size_t)bz * 2304 + rowbase + ro];
          }
#pragma unroll
          for (int nf = 0; nf < 4; nf++) {
            const int col = wc * 64 + nf * 16 + l15;
            float v = acc[mf][nf][r];
            if constexpr (MODE == 1)
              v = __expf(v);
            else if constexpr (MODE == 3)
              v = v * mulv;
            else if constexpr (MODE == 0) {
              if (roleB)
                v += bias2[colbase + col];
              else
                v += addv;
            }
            eb[lr * P + col] = f2bf(v);
          }
        }
      }
      LGKM0();
      SBAR();
#pragma unroll
      for (int i = 0; i < 8; i++) {
        const int flat = i * 512 + tid;
        const int rr = flat >> 5, cg = flat & 31;
        u16x8_t v = *(const u16x8_t*)&eb[rr * P + cg * 8];
        const int ro = (rr >> 6) * 128 + h * 64 + (rr & 63);
        *(u16x8_t*)&Cp[(size_t)(rowout0 + ro) * ldc + colbase + cg * 8] = v;
        if constexpr (MODE == 1) {
          float s8 = 0.f;
#pragma unroll
          for (int j = 0; j < 8; j++) s8 += bf2f(v[j]);
#pragma unroll
          for (int o = 1; o < 32; o <<= 1) s8 += __shfl_xor(s8, o);
          if ((l & 31) == 0)
            stats[((size_t)bz * 9 + bx) * 2304 + rowbase + ro] = s8;
        }
      }
      SBAR();
    }
  }
}

// ---------------- reduce per-row partial sums (9 col-tiles) -> 1/S -----------
__global__ __launch_bounds__(256) void reduce_sums(
    const float* __restrict__ stats, float* __restrict__ rowinv) {
  const int i = blockIdx.x * 256 + threadIdx.x;  // [0, 18432)
  const int bz = i / 2304, n = i % 2304;
  const float* s = stats + (size_t)bz * 9 * 2304 + n;
  float S = 0.f;
  for (int j = 0; j < 9; j++) S += s[(size_t)j * 2304];
  rowinv[i] = 1.0f / S;
}

extern "C" void kernel_launch(void* const* d_in, const int* in_sizes, int n_in,
                              void* d_out, int out_size, void* d_ws,
                              size_t ws_size, hipStream_t stream) {
  const float* x = (const float*)d_in[0];
  const float* w1 = (const float*)d_in[1];
  const float* b1 = (const float*)d_in[2];
  const float* w2 = (const float*)d_in[3];
  const float* b2 = (const float*)d_in[4];
  const float* w3 = (const float*)d_in[5];
  const float* b3 = (const float*)d_in[6];
  const float* w4 = (const float*)d_in[7];
  const float* b4 = (const float*)d_in[8];
  float* out = (float*)d_out;
  char* ws = (char*)d_ws;

  // B=8, HW=2304, CIN=1024, CMID=512. ws = 256 MiB:
  //  [0,84.93M)        att P' = bf16 exp(score); before att this window holds
  //                    xT(37.75M) | g_nat(18.87M) | bcat(4K) — all dead then.
  //  [84.93M,~85.6M)   partial row sums 8*9*2304 f32
  //  [87.59M,87.66M)   rowinv 8*2304 f32
  //  [169.87M)         wb 4M | theta | phiT | gT | y | yrT (18.87M each)
  if (ws_size < 268435456ull) return;
  u16* p_xT = (u16*)(ws);
  u16* p_gn = (u16*)(ws + 37748736);
  float* p_bcat = (float*)(ws + 56623104);
  u16* p_att = (u16*)(ws);
  float* p_stats = (float*)(ws + 84934656);
  float* p_rinv = (float*)(ws + 87588864);
  u16* p_wb = (u16*)(ws + 169869312);
  u16* p_theta = (u16*)(ws + 174063616);
  u16* p_phiT = (u16*)(ws + 192937984);
  u16* p_gT = (u16*)(ws + 211812352);
  u16* p_y = (u16*)(ws + 230686720);
  u16* p_yrT = (u16*)(ws + 249561088);

  // 1) weights -> bf16 as [w1; w3; w2; w4]; bias concat [b1;b3]
  cast4_kernel<<<dim3(2048, 1, 4), 256, 0, stream>>>(w1, w3, w2, w4, p_wb);
  bcat_kernel<<<dim3(4), 256, 0, stream>>>(b1, b3, p_bcat);
  // 2) xT[b] = cast(x[b])^T : [1024,2304] -> [2304,1024]
  cast_transpose_kernel<<<dim3(72, 32, 8), dim3(32, 8), 0, stream>>>(
      x, p_xT, 1024, 2304, 2359296L, 2359296L);
  // 3) conv dual-role: 288 blocks [theta;g] + 144 blocks phiT (432 total)
  gemm8<0><<<dim3(432), 512, 0, stream>>>(
      p_wb, p_xT, p_theta, p_gn, p_phiT, p_wb + 1048576, p_bcat, b2, nullptr,
      nullptr);
  // 4) gT[c][m] = (g_flat viewed [2304,512])^T  (must precede att overwrite)
  transpose64<<<dim3(8, 36, 8), 256, 0, stream>>>(p_gn, p_gT, 2304, 512,
                                                  1179648L, 1179648L);
  // 5) att: P' = bf16 exp(theta_v @ phi_v), partial row sums -> stats
  gemm8<1><<<dim3(9, 9, 8), 512, 0, stream>>>(
      p_theta, p_phiT, p_att, nullptr, nullptr, nullptr, nullptr, nullptr,
      nullptr, p_stats);
  // 6) per-row 1/S
  reduce_sums<<<dim3(72), 256, 0, stream>>>(p_stats, p_rinv);
  // 7) y = P' @ g_v * invS : 256^2 tiles, 144 blocks (18/XCD, single round)
  gemm8<3><<<dim3(2, 9, 8), 512, 0, stream>>>(
      p_att, p_gT, p_y, nullptr, nullptr, nullptr, nullptr, nullptr, nullptr,
      p_rinv);
  // 8) yrT = (y_flat viewed [512,2304])^T
  transpose64<<<dim3(36, 8, 8), 256, 0, stream>>>(p_y, p_yrT, 512, 2304,
                                                  1179648L, 1179648L);
  // 9) out = x + w4 @ y_r + b4
  gemm8<2><<<dim3(9, 4, 8), 512, 0, stream>>>(
      p_wb + 1572864, p_yrT, out, nullptr, nullptr, nullptr, b4, nullptr, x,
      nullptr);
}